// Round 7
// baseline (83656.915 us; speedup 1.0000x reference)
//
#include <hip/hip_runtime.h>
#include <hip/hip_bf16.h>
#include <math.h>

#define T_STEPS 8192
#define NN      1024
#define KWG     32       // team size: 32 WGs on ONE XCD (32 CUs share an L2)
#define RT      512
#define NWG_LAUNCH 1024  // candidates; non-claimers exit immediately
#define FAST_SPIN 24     // bounded sc0 spin before agent-scope fallback

typedef float f32x4 __attribute__((ext_vector_type(4)));

#define REP16(X) X(0) X(1) X(2) X(3) X(4) X(5) X(6) X(7) \
                 X(8) X(9) X(10) X(11) X(12) X(13) X(14) X(15)
#define REP8(X)  X(0) X(1) X(2) X(3) X(4) X(5) X(6) X(7)

__device__ __forceinline__ float fast_sigmoid(float z) {
    z = fminf(fmaxf(z, -30.f), 30.f);
    return 1.f / (1.f + __expf(-z));
}
__device__ __forceinline__ float fast_tanh(float x) {
    x = fminf(fmaxf(x, -9.f), 9.f);
    const float e = __expf(2.f * x);
    return (e - 1.f) / (e + 1.f);
}

// Two-tier store: plain store write-throughs into the home XCD's L2 (fast
// path for same-L2 readers); agent-scope mirror guarantees LLC visibility
// for the fallback. Same value twice -> no ordering hazard.
__device__ __forceinline__ void st_2way(unsigned long long* p, unsigned long long v) {
    asm volatile("global_store_dwordx2 %0, %1, off" :: "v"(p), "v"(v) : "memory");
    __hip_atomic_store(p, v, __ATOMIC_RELAXED, __HIP_MEMORY_SCOPE_AGENT);
}

// Tagged poll of two u64 slots. Fast tier: sc0 loads (bypass CU L0, read the
// XCD L2 where teammates' plain stores land). Bounded; falls back to
// agent-scope (LLC, R1-R6-proven coherent). Returns true if fast tier
// resolved BOTH slots (feeds the sticky fast-enable flag).
__device__ __forceinline__ bool poll2(const unsigned long long* pa,
                                      const unsigned long long* pb,
                                      unsigned tag, bool use_fast,
                                      unsigned long long& va, unsigned long long& vb) {
    bool fa = false, fb = false;
    if (use_fast) {
        for (int it = 0; it < FAST_SPIN; ++it) {
            unsigned long long xa, xb;
            asm volatile("global_load_dwordx2 %0, %2, off sc0\n\t"
                         "global_load_dwordx2 %1, %3, off sc0\n\t"
                         "s_waitcnt vmcnt(0)"
                         : "=&v"(xa), "=&v"(xb) : "v"(pa), "v"(pb) : "memory");
            if (!fa && (unsigned)(xa >> 32) == tag) { va = xa; fa = true; }
            if (!fb && (unsigned)(xb >> 32) == tag) { vb = xb; fb = true; }
            if (fa && fb) return true;
        }
    }
    for (;;) {
        if (!fa) {
            const unsigned long long xa =
                __hip_atomic_load(pa, __ATOMIC_RELAXED, __HIP_MEMORY_SCOPE_AGENT);
            if ((unsigned)(xa >> 32) == tag) { va = xa; fa = true; }
        }
        if (!fb) {
            const unsigned long long xb =
                __hip_atomic_load(pb, __ATOMIC_RELAXED, __HIP_MEMORY_SCOPE_AGENT);
            if ((unsigned)(xb >> 32) == tag) { vb = xb; fb = true; }
        }
        if (fa && fb) return false;
    }
}

// ---------------- GEMM: C[8192,1024] = A[8192,1024] @ W[1024,1024] + bias ----
__global__ __launch_bounds__(256) void gemm_bias(
    const float* __restrict__ A, const float* __restrict__ W,
    const float* __restrict__ bias, float* __restrict__ C)
{
    const int bn = blockIdx.x;
    const int bm = blockIdx.y;
    const int tid = threadIdx.x;

    __shared__ __align__(16) float As[16][68];
    __shared__ __align__(16) float Bs[16][68];

    const int row0 = bm * 64, col0 = bn * 64;
    const int tm = (tid >> 4) << 2;
    const int tn = (tid & 15) << 2;

    float acc[4][4] = {};

    for (int k0 = 0; k0 < 1024; k0 += 16) {
        {
            const int m = tid >> 2, kq = (tid & 3) << 2;
            const float4 v = *reinterpret_cast<const float4*>(&A[(size_t)(row0 + m) * 1024 + k0 + kq]);
            As[kq + 0][m] = v.x; As[kq + 1][m] = v.y; As[kq + 2][m] = v.z; As[kq + 3][m] = v.w;
            const int kk = tid >> 4, nq = (tid & 15) << 2;
            *reinterpret_cast<float4*>(&Bs[kk][nq]) =
                *reinterpret_cast<const float4*>(&W[(size_t)(k0 + kk) * 1024 + col0 + nq]);
        }
        __syncthreads();
#pragma unroll
        for (int k = 0; k < 16; ++k) {
            const float4 a4 = *reinterpret_cast<const float4*>(&As[k][tm]);
            const float4 b4 = *reinterpret_cast<const float4*>(&Bs[k][tn]);
            const float a[4] = {a4.x, a4.y, a4.z, a4.w};
            const float b[4] = {b4.x, b4.y, b4.z, b4.w};
#pragma unroll
            for (int i = 0; i < 4; ++i)
#pragma unroll
                for (int j = 0; j < 4; ++j) acc[i][j] += a[i] * b[j];
        }
        __syncthreads();
    }
#pragma unroll
    for (int i = 0; i < 4; ++i)
#pragma unroll
        for (int j = 0; j < 4; ++j)
            C[(size_t)(row0 + tm + i) * 1024 + col0 + tn + j] = acc[i][j] + bias[col0 + tn + j];
}

// ---------------- Recurrent scan: one XCD-local team ------------------------
// Election (R4 scheme, R5-validated XCC_ID): first CAS winner's XCD = home;
// first 32 arrivals on home claim g=0..31; everyone else exits. Exchange
// goes through the home XCD's shared L2 (plain store + sc0 poll), with an
// agent-scope mirror + fallback poll making every input state hang-proof.
__global__ __launch_bounds__(RT, 1) void gru_rec(
    const float* __restrict__ xT, const float* __restrict__ xR,
    const float* __restrict__ hRW, const float* __restrict__ hW,
    const float* __restrict__ hRB, const float* __restrict__ hB,
    const float* __restrict__ h0, float* __restrict__ out,
    unsigned long long* __restrict__ P,     // [2][KWG][NN]
    unsigned long long* __restrict__ hbc,   // [2][NN]
    unsigned int* __restrict__ elect)       // [0]=home(xcd+1) [1]=claims [2]=ready
{
    const int tid = threadIdx.x;

    __shared__ int s_g;
    if (tid == 0) {
        unsigned xcc;
        asm volatile("s_getreg_b32 %0, hwreg(HW_REG_XCC_ID)" : "=s"(xcc));
        xcc = (xcc & 0xfu) + 1u;
        const unsigned old = atomicCAS(&elect[0], 0u, xcc);
        const unsigned home = old ? old : xcc;
        int slot = -1;
        if (home == xcc) {
            const unsigned s = atomicAdd(&elect[1], 1u);
            if (s < KWG) slot = (int)s;
        }
        s_g = slot;
    }
    __syncthreads();
    const int g = s_g;
    if (g < 0) return;   // uniform across WG

    const int lane = tid & 63;
    const int wave = tid >> 6;

    __shared__ __align__(16) float hsh[1088];  // chunk c at c*68
    __shared__ __align__(16) float rh[32];

    // phase 1 mapping: column j (0..31), 16 lanes (c) split i into 64-chunks
    const int j = (wave << 2) | (lane >> 4);
    const int c = lane & 15;
    const bool leader1 = (c == 0);
    const int colj = g * 32 + j;

#define LD_W1(q) f32x4 w1_##q = { \
        hRW[(size_t)(c * 64 + 4 * q + 0) * NN + colj], \
        hRW[(size_t)(c * 64 + 4 * q + 1) * NN + colj], \
        hRW[(size_t)(c * 64 + 4 * q + 2) * NN + colj], \
        hRW[(size_t)(c * 64 + 4 * q + 3) * NN + colj] };
    REP16(LD_W1)

    const int n0 = tid, n1 = tid + RT;
    const int pi0 = n0 + (n0 >> 6) * 4, pi1 = n1 + (n1 >> 6) * 4;
#define LD_W2A(q) f32x4 w2a_##q = { \
        hW[(size_t)(g * 32 + 4 * q + 0) * NN + n0], \
        hW[(size_t)(g * 32 + 4 * q + 1) * NN + n0], \
        hW[(size_t)(g * 32 + 4 * q + 2) * NN + n0], \
        hW[(size_t)(g * 32 + 4 * q + 3) * NN + n0] };
    REP8(LD_W2A)
#define LD_W2B(q) f32x4 w2b_##q = { \
        hW[(size_t)(g * 32 + 4 * q + 0) * NN + n1], \
        hW[(size_t)(g * 32 + 4 * q + 1) * NN + n1], \
        hW[(size_t)(g * 32 + 4 * q + 2) * NN + n1], \
        hW[(size_t)(g * 32 + 4 * q + 3) * NN + n1] };
    REP8(LD_W2B)

#define PIN_W1(q)  asm volatile("" : "+v"(w1_##q));
#define PIN_W2A(q) asm volatile("" : "+v"(w2a_##q));
#define PIN_W2B(q) asm volatile("" : "+v"(w2b_##q));
    REP16(PIN_W1)
    REP8(PIN_W2A)
    REP8(PIN_W2B)

    // owner-reduce mapping: column jj (0..31) x 16 reducer lanes (cc)
    const int jj = tid >> 4, cc = tid & 15;
    const int mjj = g * 32 + jj;
    const float hBo = hB[mjj];

    const int mj = colj;
    const int pij = mj + (mj >> 6) * 4;
    const float hRBj = hRB[mj];

    hsh[pi0] = h0[n0];
    hsh[pi1] = h0[n1];
    __syncthreads();

    // one-time bounded rendezvous: align team start so startup skew can't
    // falsely disable the fast tier's sticky flags
    if (tid == 0) {
        __hip_atomic_fetch_add(&elect[2], 1u, __ATOMIC_RELAXED, __HIP_MEMORY_SCOPE_AGENT);
        const long long t0 = clock64();
        while (__hip_atomic_load(&elect[2], __ATOMIC_RELAXED, __HIP_MEMORY_SCOPE_AGENT) < KWG
               && (clock64() - t0) < (1LL << 22)) {}
    }
    __syncthreads();

    float xr_n  = leader1   ? xR[mj]  : 0.f;
    float xto_n = (cc == 0) ? xT[mjj] : 0.f;

    bool fast1 = true, fast2 = true;   // sticky per-site fast-tier enables

    for (int t = 0; t < T_STEPS; ++t) {
        const unsigned tag = (unsigned)(t + 1);
        unsigned long long* __restrict__ Pb = P   + (size_t)(t & 1) * KWG * NN;
        unsigned long long* __restrict__ Hb = hbc + (size_t)(t & 1) * NN;

        const float xr = xr_n, xto = xto_n;
        if (t + 1 < T_STEPS) {
            if (leader1) xr_n  = xR[(size_t)(t + 1) * NN + mj];
            if (cc == 0) xto_n = xT[(size_t)(t + 1) * NN + mjj];
        }

        // ---- phase 1: r-gemv partials over own 64-chunk
        f32x4 acc = {0.f, 0.f, 0.f, 0.f};
#define FMA_W1(q) { \
        const f32x4 hv = *reinterpret_cast<const f32x4*>(&hsh[c * 68 + 4 * q]); \
        acc += hv * w1_##q; }
        REP16(FMA_W1)
        float s = (acc.x + acc.y) + (acc.z + acc.w);
        s += __shfl_xor(s, 1); s += __shfl_xor(s, 2);
        s += __shfl_xor(s, 4); s += __shfl_xor(s, 8);
        if (leader1) rh[j] = fast_sigmoid(xr + hRBj + s) * hsh[pij];
        __syncthreads();

        // ---- phase 2: rank-32 partials for n0, n1 -> 2-way tagged stores
        f32x4 aa = {0.f, 0.f, 0.f, 0.f}, bb = {0.f, 0.f, 0.f, 0.f};
#define FMA_W2(q) { \
        const f32x4 rv = *reinterpret_cast<const f32x4*>(&rh[4 * q]); \
        aa += rv * w2a_##q; bb += rv * w2b_##q; }
        REP8(FMA_W2)
        const float p0 = (aa.x + aa.y) + (aa.z + aa.w);
        const float p1 = (bb.x + bb.y) + (bb.z + bb.w);
        st_2way(&Pb[(size_t)g * NN + n0],
                ((unsigned long long)tag << 32) | (unsigned)__float_as_uint(p0));
        st_2way(&Pb[(size_t)g * NN + n1],
                ((unsigned long long)tag << 32) | (unsigned)__float_as_uint(p1));

        // ---- RT1: owner-reduce — poll partials from regions cc and cc+16
        {
            unsigned long long va = 0, vb = 0;
            const bool ff = poll2(&Pb[(size_t)cc * NN + mjj],
                                  &Pb[(size_t)(cc + 16) * NN + mjj],
                                  tag, fast1, va, vb);
            fast1 = fast1 && ff;
            float s2 = __uint_as_float((unsigned)va) + __uint_as_float((unsigned)vb);
            s2 += __shfl_xor(s2, 1); s2 += __shfl_xor(s2, 2);
            s2 += __shfl_xor(s2, 4); s2 += __shfl_xor(s2, 8);
            if (cc == 0) {
                const float hn = fast_tanh(xto + s2 + hBo);
                st_2way(&Hb[mjj],
                        ((unsigned long long)tag << 32) | (unsigned)__float_as_uint(hn));
                out[(size_t)t * NN + mjj] = hn;
            }
        }

        // ---- RT2: poll h broadcast, refill LDS h
        {
            unsigned long long ua = 0, ub = 0;
            const bool ff = poll2(&Hb[n0], &Hb[n1], tag, fast2, ua, ub);
            fast2 = fast2 && ff;
            hsh[pi0] = __uint_as_float((unsigned)ua);
            hsh[pi1] = __uint_as_float((unsigned)ub);
        }
        __syncthreads();
    }
}

extern "C" void kernel_launch(void* const* d_in, const int* in_sizes, int n_in,
                              void* d_out, int out_size, void* d_ws, size_t ws_size,
                              hipStream_t stream) {
    const float* x   = (const float*)d_in[0];
    const float* Wx  = (const float*)d_in[1];
    const float* bx  = (const float*)d_in[2];
    // d_in[3]=Wu, d_in[4]=bu unused: update gate cancels in the reference
    const float* Wr  = (const float*)d_in[5];
    const float* br  = (const float*)d_in[6];
    const float* hW  = (const float*)d_in[7];
    // d_in[8]=hUW unused
    const float* hRW = (const float*)d_in[9];
    const float* hB  = (const float*)d_in[10];
    // d_in[11]=hUB unused
    const float* hRB = (const float*)d_in[12];
    const float* h0  = (const float*)d_in[13];
    float* out = (float*)d_out;

    char* ws = (char*)d_ws;
    float* xT = (float*)(ws);                    // 32 MB
    float* xR = (float*)(ws + 33554432);         // 32 MB
    unsigned int* elect = (unsigned int*)(ws + 67108864);                         // 4 KB
    unsigned long long* P   = (unsigned long long*)(ws + 67108864 + 4096);        // 512 KB
    unsigned long long* hbc = (unsigned long long*)(ws + 67108864 + 4096 + 524288); // 16 KB

    // reset election + tags every launch (graph-replayed with the kernels)
    hipMemsetAsync(ws + 67108864, 0, 4096 + 524288 + 16384, stream);

    gemm_bias<<<dim3(16, 128), 256, 0, stream>>>(x, Wx, bx, xT);
    gemm_bias<<<dim3(16, 128), 256, 0, stream>>>(x, Wr, br, xR);

    gru_rec<<<dim3(NWG_LAUNCH), RT, 0, stream>>>(xT, xR, hRW, hW, hRB, hB, h0,
                                                 out, P, hbc, elect);
}

// Round 8
// 80082.050 us; speedup vs baseline: 1.0446x; 1.0446x over previous
//
#include <hip/hip_runtime.h>
#include <hip/hip_bf16.h>
#include <math.h>

#define T_STEPS 8192
#define NN      1024
#define KWG     32
#define RT      512

typedef float f32x4 __attribute__((ext_vector_type(4)));

#define REP16(X) X(0) X(1) X(2) X(3) X(4) X(5) X(6) X(7) \
                 X(8) X(9) X(10) X(11) X(12) X(13) X(14) X(15)
#define REP8(X)  X(0) X(1) X(2) X(3) X(4) X(5) X(6) X(7)

__device__ __forceinline__ float fast_sigmoid(float z) {
    z = fminf(fmaxf(z, -30.f), 30.f);
    return 1.f / (1.f + __expf(-z));
}
__device__ __forceinline__ float fast_tanh(float x) {
    x = fminf(fmaxf(x, -9.f), 9.f);
    const float e = __expf(2.f * x);
    return (e - 1.f) / (e + 1.f);
}

// ---------------- GEMM: C[8192,1024] = A[8192,1024] @ W[1024,1024] + bias ----
__global__ __launch_bounds__(256) void gemm_bias(
    const float* __restrict__ A, const float* __restrict__ W,
    const float* __restrict__ bias, float* __restrict__ C)
{
    const int bn = blockIdx.x;
    const int bm = blockIdx.y;
    const int tid = threadIdx.x;

    __shared__ __align__(16) float As[16][68];
    __shared__ __align__(16) float Bs[16][68];

    const int row0 = bm * 64, col0 = bn * 64;
    const int tm = (tid >> 4) << 2;
    const int tn = (tid & 15) << 2;

    float acc[4][4] = {};

    for (int k0 = 0; k0 < 1024; k0 += 16) {
        {
            const int m = tid >> 2, kq = (tid & 3) << 2;
            const float4 v = *reinterpret_cast<const float4*>(&A[(size_t)(row0 + m) * 1024 + k0 + kq]);
            As[kq + 0][m] = v.x; As[kq + 1][m] = v.y; As[kq + 2][m] = v.z; As[kq + 3][m] = v.w;
            const int kk = tid >> 4, nq = (tid & 15) << 2;
            *reinterpret_cast<float4*>(&Bs[kk][nq]) =
                *reinterpret_cast<const float4*>(&W[(size_t)(k0 + kk) * 1024 + col0 + nq]);
        }
        __syncthreads();
#pragma unroll
        for (int k = 0; k < 16; ++k) {
            const float4 a4 = *reinterpret_cast<const float4*>(&As[k][tm]);
            const float4 b4 = *reinterpret_cast<const float4*>(&Bs[k][tn]);
            const float a[4] = {a4.x, a4.y, a4.z, a4.w};
            const float b[4] = {b4.x, b4.y, b4.z, b4.w};
#pragma unroll
            for (int i = 0; i < 4; ++i)
#pragma unroll
                for (int j = 0; j < 4; ++j) acc[i][j] += a[i] * b[j];
        }
        __syncthreads();
    }
#pragma unroll
    for (int i = 0; i < 4; ++i)
#pragma unroll
        for (int j = 0; j < 4; ++j)
            C[(size_t)(row0 + tm + i) * 1024 + col0 + tn + j] = acc[i][j] + bias[col0 + tn + j];
}

// ---------------- Recurrent scan: SINGLE-HOP all-to-all exchange ------------
// 32 persistent WGs (grid=32, guaranteed co-resident). Per step:
//   p1: r_j partial dots (w1 in regs) | B1
//   p2: rank-32 partials for n0,n1 -> ONE tagged agent store each (own
//       region, single writer per line, no RMW)
//   gather: EVERY WG polls all 32 regions for its two columns (batched
//       16-wide sweeps, per-group done bits), reduces locally in fixed
//       order -> h computed redundantly but bitwise-identically everywhere.
//   tanh, hsh refill, own-column out store | B2
// ONE LLC visibility+discovery chain per step (R6 had two).
// Deadlock-free with 2 buffers: WG p stores step t+2 only after gathering
// ALL of step t+1, which requires every WG to have finished step t.
__global__ __launch_bounds__(RT, 1) void gru_rec(
    const float* __restrict__ xT, const float* __restrict__ xR,
    const float* __restrict__ hRW, const float* __restrict__ hW,
    const float* __restrict__ hRB, const float* __restrict__ hB,
    const float* __restrict__ h0, float* __restrict__ out,
    unsigned long long* __restrict__ P)     // [2][KWG][NN] tagged partials
{
    const int g = blockIdx.x;
    const int tid = threadIdx.x;
    const int lane = tid & 63;
    const int wave = tid >> 6;

    __shared__ __align__(16) float hsh[1088];  // chunk c at c*68
    __shared__ __align__(16) float rh[32];

    // phase 1 mapping: column j (0..31), 16 lanes (c) split i into 64-chunks
    const int j = (wave << 2) | (lane >> 4);
    const int c = lane & 15;
    const bool leader1 = (c == 0);
    const int colj = g * 32 + j;

#define LD_W1(q) f32x4 w1_##q = { \
        hRW[(size_t)(c * 64 + 4 * q + 0) * NN + colj], \
        hRW[(size_t)(c * 64 + 4 * q + 1) * NN + colj], \
        hRW[(size_t)(c * 64 + 4 * q + 2) * NN + colj], \
        hRW[(size_t)(c * 64 + 4 * q + 3) * NN + colj] };
    REP16(LD_W1)

    const int n0 = tid, n1 = tid + RT;
    const int pi0 = n0 + (n0 >> 6) * 4, pi1 = n1 + (n1 >> 6) * 4;
#define LD_W2A(q) f32x4 w2a_##q = { \
        hW[(size_t)(g * 32 + 4 * q + 0) * NN + n0], \
        hW[(size_t)(g * 32 + 4 * q + 1) * NN + n0], \
        hW[(size_t)(g * 32 + 4 * q + 2) * NN + n0], \
        hW[(size_t)(g * 32 + 4 * q + 3) * NN + n0] };
    REP8(LD_W2A)
#define LD_W2B(q) f32x4 w2b_##q = { \
        hW[(size_t)(g * 32 + 4 * q + 0) * NN + n1], \
        hW[(size_t)(g * 32 + 4 * q + 1) * NN + n1], \
        hW[(size_t)(g * 32 + 4 * q + 2) * NN + n1], \
        hW[(size_t)(g * 32 + 4 * q + 3) * NN + n1] };
    REP8(LD_W2B)

#define PIN_W1(q)  asm volatile("" : "+v"(w1_##q));
#define PIN_W2A(q) asm volatile("" : "+v"(w2a_##q));
#define PIN_W2B(q) asm volatile("" : "+v"(w2b_##q));
    REP16(PIN_W1)
    REP8(PIN_W2A)
    REP8(PIN_W2B)

    const float hB0 = hB[n0], hB1 = hB[n1];
    const bool own0 = ((n0 >> 5) == g), own1 = ((n1 >> 5) == g);

    const int mj = colj;
    const int pij = mj + (mj >> 6) * 4;
    const float hRBj = hRB[mj];

    hsh[pi0] = h0[n0];
    hsh[pi1] = h0[n1];
    __syncthreads();

    // 16-slot batched tagged gather: issue 16 independent loads, check all
    // tags, accumulate in fixed order once complete. Per-group done bit ->
    // retries only re-poll missing groups. Static indices keep v[] in regs.
#define GATHER16(BASEPTR, SUMVAR, BIT) \
    if (!(dmask & (BIT))) { \
        unsigned long long v[16]; \
        _Pragma("unroll") \
        for (int q = 0; q < 16; ++q) \
            v[q] = __hip_atomic_load((BASEPTR) + (size_t)q * NN, \
                                     __ATOMIC_RELAXED, __HIP_MEMORY_SCOPE_AGENT); \
        bool ok = true; \
        _Pragma("unroll") \
        for (int q = 0; q < 16; ++q) \
            ok = ok && ((unsigned)(v[q] >> 32) == tag); \
        if (ok) { \
            float ssum = 0.f; \
            _Pragma("unroll") \
            for (int q = 0; q < 16; ++q) ssum += __uint_as_float((unsigned)v[q]); \
            SUMVAR = ssum; dmask |= (BIT); \
        } \
    }

    for (int t = 0; t < T_STEPS; ++t) {
        const unsigned tag = (unsigned)(t + 1);
        unsigned long long* __restrict__ Pb = P + (size_t)(t & 1) * KWG * NN;

        // inputs for this step (issued early; whole phase1/2 hides latency)
        const float xt0 = xT[(size_t)t * NN + n0];
        const float xt1 = xT[(size_t)t * NN + n1];
        const float xr = leader1 ? xR[(size_t)t * NN + mj] : 0.f;

        // ---- phase 1: r-gemv partials over own 64-chunk
        f32x4 acc = {0.f, 0.f, 0.f, 0.f};
#define FMA_W1(q) { \
        const f32x4 hv = *reinterpret_cast<const f32x4*>(&hsh[c * 68 + 4 * q]); \
        acc += hv * w1_##q; }
        REP16(FMA_W1)
        float s = (acc.x + acc.y) + (acc.z + acc.w);
        s += __shfl_xor(s, 1); s += __shfl_xor(s, 2);
        s += __shfl_xor(s, 4); s += __shfl_xor(s, 8);
        if (leader1) rh[j] = fast_sigmoid(xr + hRBj + s) * hsh[pij];
        __syncthreads();

        // ---- phase 2: rank-32 partials for n0, n1 -> single tagged store
        f32x4 aa = {0.f, 0.f, 0.f, 0.f}, bb = {0.f, 0.f, 0.f, 0.f};
#define FMA_W2(q) { \
        const f32x4 rv = *reinterpret_cast<const f32x4*>(&rh[4 * q]); \
        aa += rv * w2a_##q; bb += rv * w2b_##q; }
        REP8(FMA_W2)
        const float p0 = (aa.x + aa.y) + (aa.z + aa.w);
        const float p1 = (bb.x + bb.y) + (bb.z + bb.w);
        __hip_atomic_store(&Pb[(size_t)g * NN + n0],
            ((unsigned long long)tag << 32) | (unsigned)__float_as_uint(p0),
            __ATOMIC_RELAXED, __HIP_MEMORY_SCOPE_AGENT);
        __hip_atomic_store(&Pb[(size_t)g * NN + n1],
            ((unsigned long long)tag << 32) | (unsigned)__float_as_uint(p1),
            __ATOMIC_RELAXED, __HIP_MEMORY_SCOPE_AGENT);

        // ---- gather: all 32 regions for both columns, redundant reduce
        unsigned dmask = 0;
        float s0a = 0.f, s0b = 0.f, s1a = 0.f, s1b = 0.f;
        const unsigned long long* Pb0  = Pb + n0;
        const unsigned long long* Pb0h = Pb + (size_t)16 * NN + n0;
        const unsigned long long* Pb1  = Pb + n1;
        const unsigned long long* Pb1h = Pb + (size_t)16 * NN + n1;
        do {
            GATHER16(Pb0,  s0a, 1u)
            GATHER16(Pb0h, s0b, 2u)
            GATHER16(Pb1,  s1a, 4u)
            GATHER16(Pb1h, s1b, 8u)
        } while (dmask != 15u);

        const float hn0 = fast_tanh(xt0 + (s0a + s0b) + hB0);
        const float hn1 = fast_tanh(xt1 + (s1a + s1b) + hB1);
        hsh[pi0] = hn0;
        hsh[pi1] = hn1;
        if (own0) out[(size_t)t * NN + n0] = hn0;
        if (own1) out[(size_t)t * NN + n1] = hn1;
        __syncthreads();
    }
}

extern "C" void kernel_launch(void* const* d_in, const int* in_sizes, int n_in,
                              void* d_out, int out_size, void* d_ws, size_t ws_size,
                              hipStream_t stream) {
    const float* x   = (const float*)d_in[0];
    const float* Wx  = (const float*)d_in[1];
    const float* bx  = (const float*)d_in[2];
    // d_in[3]=Wu, d_in[4]=bu unused: update gate cancels in the reference
    const float* Wr  = (const float*)d_in[5];
    const float* br  = (const float*)d_in[6];
    const float* hW  = (const float*)d_in[7];
    // d_in[8]=hUW unused
    const float* hRW = (const float*)d_in[9];
    const float* hB  = (const float*)d_in[10];
    // d_in[11]=hUB unused
    const float* hRB = (const float*)d_in[12];
    const float* h0  = (const float*)d_in[13];
    float* out = (float*)d_out;

    char* ws = (char*)d_ws;
    float* xT = (float*)(ws);                               // 32 MB
    float* xR = (float*)(ws + 33554432);                    // 32 MB
    unsigned long long* P = (unsigned long long*)(ws + 67108864); // 512 KB

    // zero tags every launch (covers harness poison + graph replays)
    hipMemsetAsync(P, 0, (size_t)2 * KWG * NN * sizeof(unsigned long long), stream);

    gemm_bias<<<dim3(16, 128), 256, 0, stream>>>(x, Wx, bx, xT);
    gemm_bias<<<dim3(16, 128), 256, 0, stream>>>(x, Wr, br, xR);

    gru_rec<<<dim3(KWG), RT, 0, stream>>>(xT, xR, hRW, hW, hRB, hB, h0, out, P);
}

// Round 9
// 57417.523 us; speedup vs baseline: 1.4570x; 1.3947x over previous
//
#include <hip/hip_runtime.h>
#include <hip/hip_bf16.h>
#include <math.h>

#define T_STEPS 8192
#define NN      1024
#define KWG     32
#define RT      512

typedef float f32x4 __attribute__((ext_vector_type(4)));

#define REP16(X) X(0) X(1) X(2) X(3) X(4) X(5) X(6) X(7) \
                 X(8) X(9) X(10) X(11) X(12) X(13) X(14) X(15)
#define REP8(X)  X(0) X(1) X(2) X(3) X(4) X(5) X(6) X(7)

__device__ __forceinline__ float fast_sigmoid(float z) {
    z = fminf(fmaxf(z, -30.f), 30.f);
    return 1.f / (1.f + __expf(-z));
}
__device__ __forceinline__ float fast_tanh(float x) {
    x = fminf(fmaxf(x, -9.f), 9.f);
    const float e = __expf(2.f * x);
    return (e - 1.f) / (e + 1.f);
}

// Raw barrier: orders LDS ops only (lgkmcnt), does NOT drain vmcnt.
// __syncthreads would force s_waitcnt vmcnt(0), stalling on in-flight HBM
// prefetches and dangling poll loads -- the ~700cy/step tax found in R6.
__device__ __forceinline__ void sync_lds() {
    asm volatile("s_waitcnt lgkmcnt(0)\n\ts_barrier" ::: "memory");
}

__device__ __forceinline__ unsigned long long ld_agent(const unsigned long long* p) {
    return __hip_atomic_load(p, __ATOMIC_RELAXED, __HIP_MEMORY_SCOPE_AGENT);
}

// 4-deep software-pipelined tagged poll of two slots: 8 loads in flight,
// check oldest, reissue. Sampling period ~ LLC-latency/4 instead of 1x ->
// cuts average discovery overshoot ~450cy/hop. Dangling loads at exit are
// never drained (raw barriers) -- values simply discarded.
__device__ __forceinline__ void poll2_pipe(const unsigned long long* pa,
                                           const unsigned long long* pb,
                                           unsigned tag,
                                           unsigned long long& va,
                                           unsigned long long& vb) {
    unsigned long long A0 = ld_agent(pa), B0 = ld_agent(pb);
    unsigned long long A1 = ld_agent(pa), B1 = ld_agent(pb);
    unsigned long long A2 = ld_agent(pa), B2 = ld_agent(pb);
    unsigned long long A3 = ld_agent(pa), B3 = ld_agent(pb);
    bool fa = false, fb = false;
#define CHK(Aq, Bq) \
    if (!fa && (unsigned)(Aq >> 32) == tag) { va = Aq; fa = true; } \
    if (!fb && (unsigned)(Bq >> 32) == tag) { vb = Bq; fb = true; } \
    if (fa && fb) return; \
    Aq = ld_agent(pa); Bq = ld_agent(pb);
    for (;;) {
        CHK(A0, B0)
        CHK(A1, B1)
        CHK(A2, B2)
        CHK(A3, B3)
    }
#undef CHK
}

// ---------------- GEMM: C[8192,1024] = A[8192,1024] @ W[1024,1024] + bias ----
__global__ __launch_bounds__(256) void gemm_bias(
    const float* __restrict__ A, const float* __restrict__ W,
    const float* __restrict__ bias, float* __restrict__ C)
{
    const int bn = blockIdx.x;
    const int bm = blockIdx.y;
    const int tid = threadIdx.x;

    __shared__ __align__(16) float As[16][68];
    __shared__ __align__(16) float Bs[16][68];

    const int row0 = bm * 64, col0 = bn * 64;
    const int tm = (tid >> 4) << 2;
    const int tn = (tid & 15) << 2;

    float acc[4][4] = {};

    for (int k0 = 0; k0 < 1024; k0 += 16) {
        {
            const int m = tid >> 2, kq = (tid & 3) << 2;
            const float4 v = *reinterpret_cast<const float4*>(&A[(size_t)(row0 + m) * 1024 + k0 + kq]);
            As[kq + 0][m] = v.x; As[kq + 1][m] = v.y; As[kq + 2][m] = v.z; As[kq + 3][m] = v.w;
            const int kk = tid >> 4, nq = (tid & 15) << 2;
            *reinterpret_cast<float4*>(&Bs[kk][nq]) =
                *reinterpret_cast<const float4*>(&W[(size_t)(k0 + kk) * 1024 + col0 + nq]);
        }
        __syncthreads();
#pragma unroll
        for (int k = 0; k < 16; ++k) {
            const float4 a4 = *reinterpret_cast<const float4*>(&As[k][tm]);
            const float4 b4 = *reinterpret_cast<const float4*>(&Bs[k][tn]);
            const float a[4] = {a4.x, a4.y, a4.z, a4.w};
            const float b[4] = {b4.x, b4.y, b4.z, b4.w};
#pragma unroll
            for (int i = 0; i < 4; ++i)
#pragma unroll
                for (int j = 0; j < 4; ++j) acc[i][j] += a[i] * b[j];
        }
        __syncthreads();
    }
#pragma unroll
    for (int i = 0; i < 4; ++i)
#pragma unroll
        for (int j = 0; j < 4; ++j)
            C[(size_t)(row0 + tm + i) * 1024 + col0 + tn + j] = acc[i][j] + bias[col0 + tn + j];
}

// ---------------- Recurrent scan: R6 owner-reduce, de-stalled ---------------
// 32 persistent WGs. Per step:
//   p1: r-gemv partials (w1 regs) | B1(raw)
//   prefetch xr/xto for t+1 (drains never forced -- raw barriers)
//   p2: rank-32 partials -> tagged agent stores
//   RT1: owner pipeline-polls 32 partials (1 poller/slot), shfl-reduce,
//        tanh -> tagged h store + out store (lane cc==0)
//   RT2: all pipeline-poll tagged h, refill LDS | B2(raw)
__global__ __launch_bounds__(RT, 1) void gru_rec(
    const float* __restrict__ xT, const float* __restrict__ xR,
    const float* __restrict__ hRW, const float* __restrict__ hW,
    const float* __restrict__ hRB, const float* __restrict__ hB,
    const float* __restrict__ h0, float* __restrict__ out,
    unsigned long long* __restrict__ P,     // [2][KWG][NN]
    unsigned long long* __restrict__ hbc)   // [2][NN]
{
    const int g = blockIdx.x;
    const int tid = threadIdx.x;
    const int lane = tid & 63;
    const int wave = tid >> 6;

    __shared__ __align__(16) float hsh[1088];  // chunk c at c*68
    __shared__ __align__(16) float rh[32];

    // phase 1 mapping: column j (0..31), 16 lanes (c) split i into 64-chunks
    const int j = (wave << 2) | (lane >> 4);
    const int c = lane & 15;
    const bool leader1 = (c == 0);
    const int colj = g * 32 + j;

#define LD_W1(q) f32x4 w1_##q = { \
        hRW[(size_t)(c * 64 + 4 * q + 0) * NN + colj], \
        hRW[(size_t)(c * 64 + 4 * q + 1) * NN + colj], \
        hRW[(size_t)(c * 64 + 4 * q + 2) * NN + colj], \
        hRW[(size_t)(c * 64 + 4 * q + 3) * NN + colj] };
    REP16(LD_W1)

    const int n0 = tid, n1 = tid + RT;
    const int pi0 = n0 + (n0 >> 6) * 4, pi1 = n1 + (n1 >> 6) * 4;
#define LD_W2A(q) f32x4 w2a_##q = { \
        hW[(size_t)(g * 32 + 4 * q + 0) * NN + n0], \
        hW[(size_t)(g * 32 + 4 * q + 1) * NN + n0], \
        hW[(size_t)(g * 32 + 4 * q + 2) * NN + n0], \
        hW[(size_t)(g * 32 + 4 * q + 3) * NN + n0] };
    REP8(LD_W2A)
#define LD_W2B(q) f32x4 w2b_##q = { \
        hW[(size_t)(g * 32 + 4 * q + 0) * NN + n1], \
        hW[(size_t)(g * 32 + 4 * q + 1) * NN + n1], \
        hW[(size_t)(g * 32 + 4 * q + 2) * NN + n1], \
        hW[(size_t)(g * 32 + 4 * q + 3) * NN + n1] };
    REP8(LD_W2B)

#define PIN_W1(q)  asm volatile("" : "+v"(w1_##q));
#define PIN_W2A(q) asm volatile("" : "+v"(w2a_##q));
#define PIN_W2B(q) asm volatile("" : "+v"(w2b_##q));
    REP16(PIN_W1)
    REP8(PIN_W2A)
    REP8(PIN_W2B)

    // owner-reduce mapping: column jj (0..31) x 16 reducer lanes (cc)
    const int jj = tid >> 4, cc = tid & 15;
    const int mjj = g * 32 + jj;
    const float hBo = hB[mjj];

    const int mj = colj;
    const int pij = mj + (mj >> 6) * 4;
    const float hRBj = hRB[mj];

    hsh[pi0] = h0[n0];
    hsh[pi1] = h0[n1];
    __syncthreads();

    // current-step inputs (prologue); in-loop prefetch happens AFTER B1 so
    // the loads are ~a full step old before anything could wait on them.
    float xr_c  = leader1   ? xR[mj]  : 0.f;
    float xto_c = (cc == 0) ? xT[mjj] : 0.f;

    for (int t = 0; t < T_STEPS; ++t) {
        const unsigned tag = (unsigned)(t + 1);
        unsigned long long* __restrict__ Pb = P   + (size_t)(t & 1) * KWG * NN;
        unsigned long long* __restrict__ Hb = hbc + (size_t)(t & 1) * NN;

        // ---- phase 1: r-gemv partials over own 64-chunk
        f32x4 acc = {0.f, 0.f, 0.f, 0.f};
#define FMA_W1(q) { \
        const f32x4 hv = *reinterpret_cast<const f32x4*>(&hsh[c * 68 + 4 * q]); \
        acc += hv * w1_##q; }
        REP16(FMA_W1)
        float s = (acc.x + acc.y) + (acc.z + acc.w);
        s += __shfl_xor(s, 1); s += __shfl_xor(s, 2);
        s += __shfl_xor(s, 4); s += __shfl_xor(s, 8);
        if (leader1) rh[j] = fast_sigmoid(xr_c + hRBj + s) * hsh[pij];
        sync_lds();   // B1: rh visible; no vmcnt drain

        // ---- prefetch t+1 inputs (issued here, never force-drained)
        float xr_nx = 0.f, xto_nx = 0.f;
        if (t + 1 < T_STEPS) {
            if (leader1) xr_nx  = xR[(size_t)(t + 1) * NN + mj];
            if (cc == 0) xto_nx = xT[(size_t)(t + 1) * NN + mjj];
        }

        // ---- phase 2: rank-32 partials for n0, n1 -> tagged agent stores
        f32x4 aa = {0.f, 0.f, 0.f, 0.f}, bb = {0.f, 0.f, 0.f, 0.f};
#define FMA_W2(q) { \
        const f32x4 rv = *reinterpret_cast<const f32x4*>(&rh[4 * q]); \
        aa += rv * w2a_##q; bb += rv * w2b_##q; }
        REP8(FMA_W2)
        const float p0 = (aa.x + aa.y) + (aa.z + aa.w);
        const float p1 = (bb.x + bb.y) + (bb.z + bb.w);
        __hip_atomic_store(&Pb[(size_t)g * NN + n0],
            ((unsigned long long)tag << 32) | (unsigned)__float_as_uint(p0),
            __ATOMIC_RELAXED, __HIP_MEMORY_SCOPE_AGENT);
        __hip_atomic_store(&Pb[(size_t)g * NN + n1],
            ((unsigned long long)tag << 32) | (unsigned)__float_as_uint(p1),
            __ATOMIC_RELAXED, __HIP_MEMORY_SCOPE_AGENT);

        // ---- RT1: owner-reduce (pipelined poll of regions cc and cc+16)
        {
            unsigned long long va = 0, vb = 0;
            poll2_pipe(&Pb[(size_t)cc * NN + mjj],
                       &Pb[(size_t)(cc + 16) * NN + mjj], tag, va, vb);
            float s2 = __uint_as_float((unsigned)va) + __uint_as_float((unsigned)vb);
            s2 += __shfl_xor(s2, 1); s2 += __shfl_xor(s2, 2);
            s2 += __shfl_xor(s2, 4); s2 += __shfl_xor(s2, 8);
            if (cc == 0) {
                const float hn = fast_tanh(xto_c + s2 + hBo);
                __hip_atomic_store(&Hb[mjj],
                    ((unsigned long long)tag << 32) | (unsigned)__float_as_uint(hn),
                    __ATOMIC_RELAXED, __HIP_MEMORY_SCOPE_AGENT);
                out[(size_t)t * NN + mjj] = hn;
            }
        }

        // ---- RT2: pipelined poll of h broadcast, refill LDS h
        {
            unsigned long long ua = 0, ub = 0;
            poll2_pipe(&Hb[n0], &Hb[n1], tag, ua, ub);
            hsh[pi0] = __uint_as_float((unsigned)ua);
            hsh[pi1] = __uint_as_float((unsigned)ub);
        }
        xr_c = xr_nx;
        xto_c = xto_nx;
        sync_lds();   // B2: hsh consistent; no vmcnt drain
    }
}

extern "C" void kernel_launch(void* const* d_in, const int* in_sizes, int n_in,
                              void* d_out, int out_size, void* d_ws, size_t ws_size,
                              hipStream_t stream) {
    const float* x   = (const float*)d_in[0];
    const float* Wx  = (const float*)d_in[1];
    const float* bx  = (const float*)d_in[2];
    // d_in[3]=Wu, d_in[4]=bu unused: update gate cancels in the reference
    const float* Wr  = (const float*)d_in[5];
    const float* br  = (const float*)d_in[6];
    const float* hW  = (const float*)d_in[7];
    // d_in[8]=hUW unused
    const float* hRW = (const float*)d_in[9];
    const float* hB  = (const float*)d_in[10];
    // d_in[11]=hUB unused
    const float* hRB = (const float*)d_in[12];
    const float* h0  = (const float*)d_in[13];
    float* out = (float*)d_out;

    char* ws = (char*)d_ws;
    float* xT = (float*)(ws);                               // 32 MB
    float* xR = (float*)(ws + 33554432);                    // 32 MB
    unsigned long long* P   = (unsigned long long*)(ws + 67108864);          // 512 KB
    unsigned long long* hbc = (unsigned long long*)(ws + 67108864 + 524288); // 16 KB

    // clear tags every launch (covers harness poison; replays are identical)
    hipMemsetAsync(P, 0, (2 * KWG * NN + 2 * NN) * sizeof(unsigned long long), stream);

    gemm_bias<<<dim3(16, 128), 256, 0, stream>>>(x, Wx, bx, xT);
    gemm_bias<<<dim3(16, 128), 256, 0, stream>>>(x, Wr, br, xR);

    gru_rec<<<dim3(KWG), RT, 0, stream>>>(xT, xR, hRW, hW, hRB, hB, h0,
                                          out, P, hbc);
}

// Round 10
// 38351.129 us; speedup vs baseline: 2.1813x; 1.4972x over previous
//
#include <hip/hip_runtime.h>
#include <hip/hip_bf16.h>
#include <math.h>

#define T_STEPS 8192
#define NN      1024
#define KWG     32
#define RT      512
#define NREP    4    // replica slots per output: 8 serialized RMWs/line, not 32

typedef float f32x4 __attribute__((ext_vector_type(4)));
typedef unsigned long long u64;

#define REP16(X) X(0) X(1) X(2) X(3) X(4) X(5) X(6) X(7) \
                 X(8) X(9) X(10) X(11) X(12) X(13) X(14) X(15)
#define REP8(X)  X(0) X(1) X(2) X(3) X(4) X(5) X(6) X(7)

__device__ __forceinline__ float fast_sigmoid(float z) {
    z = fminf(fmaxf(z, -30.f), 30.f);
    return 1.f / (1.f + __expf(-z));
}
__device__ __forceinline__ float fast_tanh(float x) {
    x = fminf(fmaxf(x, -9.f), 9.f);
    const float e = __expf(2.f * x);
    return (e - 1.f) / (e + 1.f);
}

// ---------------- GEMM: C[8192,1024] = A[8192,1024] @ W[1024,1024] + bias ----
__global__ __launch_bounds__(256) void gemm_bias(
    const float* __restrict__ A, const float* __restrict__ W,
    const float* __restrict__ bias, float* __restrict__ C)
{
    const int bn = blockIdx.x;
    const int bm = blockIdx.y;
    const int tid = threadIdx.x;

    __shared__ __align__(16) float As[16][68];
    __shared__ __align__(16) float Bs[16][68];

    const int row0 = bm * 64, col0 = bn * 64;
    const int tm = (tid >> 4) << 2;
    const int tn = (tid & 15) << 2;

    float acc[4][4] = {};

    for (int k0 = 0; k0 < 1024; k0 += 16) {
        {
            const int m = tid >> 2, kq = (tid & 3) << 2;
            const float4 v = *reinterpret_cast<const float4*>(&A[(size_t)(row0 + m) * 1024 + k0 + kq]);
            As[kq + 0][m] = v.x; As[kq + 1][m] = v.y; As[kq + 2][m] = v.z; As[kq + 3][m] = v.w;
            const int kk = tid >> 4, nq = (tid & 15) << 2;
            *reinterpret_cast<float4*>(&Bs[kk][nq]) =
                *reinterpret_cast<const float4*>(&W[(size_t)(k0 + kk) * 1024 + col0 + nq]);
        }
        __syncthreads();
#pragma unroll
        for (int k = 0; k < 16; ++k) {
            const float4 a4 = *reinterpret_cast<const float4*>(&As[k][tm]);
            const float4 b4 = *reinterpret_cast<const float4*>(&Bs[k][tn]);
            const float a[4] = {a4.x, a4.y, a4.z, a4.w};
            const float b[4] = {b4.x, b4.y, b4.z, b4.w};
#pragma unroll
            for (int i = 0; i < 4; ++i)
#pragma unroll
                for (int j = 0; j < 4; ++j) acc[i][j] += a[i] * b[j];
        }
        __syncthreads();
    }
#pragma unroll
    for (int i = 0; i < 4; ++i)
#pragma unroll
        for (int j = 0; j < 4; ++j)
            C[(size_t)(row0 + tm + i) * 1024 + col0 + tn + j] = acc[i][j] + bias[col0 + tn + j];
}

// ---------------- Recurrent scan: ONE-hop fused reduce-broadcast ------------
// 32 persistent WGs (grid=32). Per step:
//   p1: r computed fully locally (own 32 cols x full h, w1 in regs) | B1
//   p2: rank-32 partials -> u64 atomicAdd of (1<<44)+fix20(p) into replica
//       slot (g&3) of each output: the count field IS the completion flag,
//       and the accumulated value IS the reduced result (reduce+broadcast
//       in a single LLC hop; integer adds = bit-deterministic).
//   poll: each thread self-throttle-polls its 2 outputs x 4 replicas until
//         all per-replica counts hit the cumulative target; sum, subtract
//         prev (regs), tanh, refill LDS h, own-column out | B2
// No zeroing: double-buffered mod 2; count@44 with cumulative payload drift
// < 2^41 << 2^43 over all 4096 reuses (R2's bit-38 margin was luck).
// Deadlock-free: a WG adds buffer b's use k+1 only after passing use k's
// poll of the OTHER buffer, which needs all WGs' adds there, which needs
// them past use k of b (R2-proven chain).
__global__ __launch_bounds__(RT, 1) void gru_rec(
    const float* __restrict__ xT, const float* __restrict__ xR,
    const float* __restrict__ hRW, const float* __restrict__ hW,
    const float* __restrict__ hRB, const float* __restrict__ hB,
    const float* __restrict__ h0, float* __restrict__ out,
    u64* __restrict__ R)     // [2][NREP][NN]
{
    const int g = blockIdx.x;
    const int tid = threadIdx.x;
    const int lane = tid & 63;
    const int wave = tid >> 6;

    __shared__ __align__(16) float hsh[1088];  // chunk c at c*68
    __shared__ __align__(16) float rh[32];

    // phase 1 mapping: own column j (0..31), 16 lanes (c) split i 64-chunks
    const int j = (wave << 2) | (lane >> 4);
    const int c = lane & 15;
    const bool leader1 = (c == 0);
    const int colj = g * 32 + j;

#define LD_W1(q) f32x4 w1_##q = { \
        hRW[(size_t)(c * 64 + 4 * q + 0) * NN + colj], \
        hRW[(size_t)(c * 64 + 4 * q + 1) * NN + colj], \
        hRW[(size_t)(c * 64 + 4 * q + 2) * NN + colj], \
        hRW[(size_t)(c * 64 + 4 * q + 3) * NN + colj] };
    REP16(LD_W1)

    const int n0 = tid, n1 = tid + RT;
    const int pi0 = n0 + (n0 >> 6) * 4, pi1 = n1 + (n1 >> 6) * 4;
#define LD_W2A(q) f32x4 w2a_##q = { \
        hW[(size_t)(g * 32 + 4 * q + 0) * NN + n0], \
        hW[(size_t)(g * 32 + 4 * q + 1) * NN + n0], \
        hW[(size_t)(g * 32 + 4 * q + 2) * NN + n0], \
        hW[(size_t)(g * 32 + 4 * q + 3) * NN + n0] };
    REP8(LD_W2A)
#define LD_W2B(q) f32x4 w2b_##q = { \
        hW[(size_t)(g * 32 + 4 * q + 0) * NN + n1], \
        hW[(size_t)(g * 32 + 4 * q + 1) * NN + n1], \
        hW[(size_t)(g * 32 + 4 * q + 2) * NN + n1], \
        hW[(size_t)(g * 32 + 4 * q + 3) * NN + n1] };
    REP8(LD_W2B)

#define PIN_W1(q)  asm volatile("" : "+v"(w1_##q));
#define PIN_W2A(q) asm volatile("" : "+v"(w2a_##q));
#define PIN_W2B(q) asm volatile("" : "+v"(w2b_##q));
    REP16(PIN_W1)
    REP8(PIN_W2A)
    REP8(PIN_W2B)

    const float hB0 = hB[n0], hB1 = hB[n1];
    const bool own0 = ((n0 >> 5) == g), own1 = ((n1 >> 5) == g);

    const int mj = colj;
    const int pij = mj + (mj >> 6) * 4;
    const float hRBj = hRB[mj];
    const int rep = g & (NREP - 1);

    hsh[pi0] = h0[n0];
    hsh[pi1] = h0[n1];
    __syncthreads();

    u64 pv00 = 0, pv01 = 0, pv10 = 0, pv11 = 0;  // prev sums per buffer/output
    u64 tgA = 0, tgB = 0;                         // per-replica count targets
    const float SC = 1048576.f, ISC = 1.f / 1048576.f;

    float xr_c = leader1 ? xR[mj] : 0.f;

#define LDA(p) __hip_atomic_load((p), __ATOMIC_RELAXED, __HIP_MEMORY_SCOPE_AGENT)
#define CNT_OK(v, T) ((((v) + (1ull << 43)) >> 44) >= (T))

#define GRU_STEP(T_, RB_, PV0_, PV1_, TG_) do { \
    const float xt0 = xT[(size_t)(T_) * NN + n0]; \
    const float xt1 = xT[(size_t)(T_) * NN + n1]; \
    /* phase 1: r for own 32 columns, fully local */ \
    f32x4 acc = {0.f, 0.f, 0.f, 0.f}; \
    REP16(FMA_W1) \
    float s = (acc.x + acc.y) + (acc.z + acc.w); \
    s += __shfl_xor(s, 1); s += __shfl_xor(s, 2); \
    s += __shfl_xor(s, 4); s += __shfl_xor(s, 8); \
    if (leader1) rh[j] = fast_sigmoid(xr_c + hRBj + s) * hsh[pij]; \
    __syncthreads(); \
    if (leader1 && (T_) + 1 < T_STEPS) xr_c = xR[(size_t)((T_) + 1) * NN + mj]; \
    /* phase 2: rank-32 partials -> tagged atomic adds (fire & forget) */ \
    f32x4 aa = {0.f, 0.f, 0.f, 0.f}, bb = {0.f, 0.f, 0.f, 0.f}; \
    REP8(FMA_W2) \
    const float p0 = (aa.x + aa.y) + (aa.z + aa.w); \
    const float p1 = (bb.x + bb.y) + (bb.z + bb.w); \
    const u64 q0 = (1ull << 44) + (u64)(long long)llrintf(p0 * SC); \
    const u64 q1 = (1ull << 44) + (u64)(long long)llrintf(p1 * SC); \
    __hip_atomic_fetch_add(&(RB_)[(size_t)rep * NN + n0], q0, \
                           __ATOMIC_RELAXED, __HIP_MEMORY_SCOPE_AGENT); \
    __hip_atomic_fetch_add(&(RB_)[(size_t)rep * NN + n1], q1, \
                           __ATOMIC_RELAXED, __HIP_MEMORY_SCOPE_AGENT); \
    TG_ += 8; \
    /* fused reduce-broadcast: self-throttled poll of 4 replicas x 2 outs */ \
    u64 v0, v1, v2, v3, w0, w1, w2, w3; \
    bool ok; \
    do { \
        v0 = LDA(&(RB_)[0 * NN + n0]); v1 = LDA(&(RB_)[1 * NN + n0]); \
        v2 = LDA(&(RB_)[2 * NN + n0]); v3 = LDA(&(RB_)[3 * NN + n0]); \
        w0 = LDA(&(RB_)[0 * NN + n1]); w1 = LDA(&(RB_)[1 * NN + n1]); \
        w2 = LDA(&(RB_)[2 * NN + n1]); w3 = LDA(&(RB_)[3 * NN + n1]); \
        ok = CNT_OK(v0, TG_) && CNT_OK(v1, TG_) && CNT_OK(v2, TG_) && CNT_OK(v3, TG_) \
          && CNT_OK(w0, TG_) && CNT_OK(w1, TG_) && CNT_OK(w2, TG_) && CNT_OK(w3, TG_); \
    } while (!ok); \
    const u64 s0 = v0 + v1 + v2 + v3; \
    const u64 s1 = w0 + w1 + w2 + w3; \
    const long long d0 = (long long)(s0 - PV0_ - ((u64)(8 * NREP) << 44)); \
    const long long d1 = (long long)(s1 - PV1_ - ((u64)(8 * NREP) << 44)); \
    PV0_ = s0; PV1_ = s1; \
    const float hn0 = fast_tanh(xt0 + (float)d0 * ISC + hB0); \
    const float hn1 = fast_tanh(xt1 + (float)d1 * ISC + hB1); \
    hsh[pi0] = hn0; hsh[pi1] = hn1; \
    if (own0) out[(size_t)(T_) * NN + n0] = hn0; \
    if (own1) out[(size_t)(T_) * NN + n1] = hn1; \
    __syncthreads(); \
} while (0)

#define FMA_W1(q) { \
        const f32x4 hv = *reinterpret_cast<const f32x4*>(&hsh[c * 68 + 4 * q]); \
        acc += hv * w1_##q; }
#define FMA_W2(q) { \
        const f32x4 rv = *reinterpret_cast<const f32x4*>(&rh[4 * q]); \
        aa += rv * w2a_##q; bb += rv * w2b_##q; }

    for (int t = 0; t < T_STEPS; t += 2) {
        GRU_STEP(t,     R,                      pv00, pv01, tgA);
        GRU_STEP(t + 1, R + (size_t)NREP * NN,  pv10, pv11, tgB);
    }
}

extern "C" void kernel_launch(void* const* d_in, const int* in_sizes, int n_in,
                              void* d_out, int out_size, void* d_ws, size_t ws_size,
                              hipStream_t stream) {
    const float* x   = (const float*)d_in[0];
    const float* Wx  = (const float*)d_in[1];
    const float* bx  = (const float*)d_in[2];
    // d_in[3]=Wu, d_in[4]=bu unused: update gate cancels in the reference
    const float* Wr  = (const float*)d_in[5];
    const float* br  = (const float*)d_in[6];
    const float* hW  = (const float*)d_in[7];
    // d_in[8]=hUW unused
    const float* hRW = (const float*)d_in[9];
    const float* hB  = (const float*)d_in[10];
    // d_in[11]=hUB unused
    const float* hRB = (const float*)d_in[12];
    const float* h0  = (const float*)d_in[13];
    float* out = (float*)d_out;

    char* ws = (char*)d_ws;
    float* xT = (float*)(ws);                               // 32 MB
    float* xR = (float*)(ws + 33554432);                    // 32 MB
    u64* R = (u64*)(ws + 67108864);                         // 64 KB

    // zero accumulators every launch (counts/payloads restart per launch;
    // graph replays re-run this memset, so replays are deterministic)
    hipMemsetAsync(R, 0, (size_t)2 * NREP * NN * sizeof(u64), stream);

    gemm_bias<<<dim3(16, 128), 256, 0, stream>>>(x, Wx, bx, xT);
    gemm_bias<<<dim3(16, 128), 256, 0, stream>>>(x, Wr, br, xR);

    gru_rec<<<dim3(KWG), RT, 0, stream>>>(xT, xR, hRW, hW, hRB, hB, h0, out, R);
}

// Round 11
// 31288.049 us; speedup vs baseline: 2.6738x; 1.2257x over previous
//
#include <hip/hip_runtime.h>
#include <hip/hip_bf16.h>
#include <math.h>

#define T_STEPS 8192
#define NN      1024
#define KWG     32
#define RT      512

typedef float f32x4 __attribute__((ext_vector_type(4)));

#define REP16(X) X(0) X(1) X(2) X(3) X(4) X(5) X(6) X(7) \
                 X(8) X(9) X(10) X(11) X(12) X(13) X(14) X(15)
#define REP8(X)  X(0) X(1) X(2) X(3) X(4) X(5) X(6) X(7)

__device__ __forceinline__ float fast_sigmoid(float z) {
    z = fminf(fmaxf(z, -30.f), 30.f);
    return 1.f / (1.f + __expf(-z));
}
__device__ __forceinline__ float fast_tanh(float x) {
    x = fminf(fmaxf(x, -9.f), 9.f);
    const float e = __expf(2.f * x);
    return (e - 1.f) / (e + 1.f);
}

// ---------------- GEMM: C[8192,1024] = A[8192,1024] @ W[1024,1024] + bias ----
__global__ __launch_bounds__(256) void gemm_bias(
    const float* __restrict__ A, const float* __restrict__ W,
    const float* __restrict__ bias, float* __restrict__ C)
{
    const int bn = blockIdx.x;
    const int bm = blockIdx.y;
    const int tid = threadIdx.x;

    __shared__ __align__(16) float As[16][68];
    __shared__ __align__(16) float Bs[16][68];

    const int row0 = bm * 64, col0 = bn * 64;
    const int tm = (tid >> 4) << 2;
    const int tn = (tid & 15) << 2;

    float acc[4][4] = {};

    for (int k0 = 0; k0 < 1024; k0 += 16) {
        {
            const int m = tid >> 2, kq = (tid & 3) << 2;
            const float4 v = *reinterpret_cast<const float4*>(&A[(size_t)(row0 + m) * 1024 + k0 + kq]);
            As[kq + 0][m] = v.x; As[kq + 1][m] = v.y; As[kq + 2][m] = v.z; As[kq + 3][m] = v.w;
            const int kk = tid >> 4, nq = (tid & 15) << 2;
            *reinterpret_cast<float4*>(&Bs[kk][nq]) =
                *reinterpret_cast<const float4*>(&W[(size_t)(k0 + kk) * 1024 + col0 + nq]);
        }
        __syncthreads();
#pragma unroll
        for (int k = 0; k < 16; ++k) {
            const float4 a4 = *reinterpret_cast<const float4*>(&As[k][tm]);
            const float4 b4 = *reinterpret_cast<const float4*>(&Bs[k][tn]);
            const float a[4] = {a4.x, a4.y, a4.z, a4.w};
            const float b[4] = {b4.x, b4.y, b4.z, b4.w};
#pragma unroll
            for (int i = 0; i < 4; ++i)
#pragma unroll
                for (int j = 0; j < 4; ++j) acc[i][j] += a[i] * b[j];
        }
        __syncthreads();
    }
#pragma unroll
    for (int i = 0; i < 4; ++i)
#pragma unroll
        for (int j = 0; j < 4; ++j)
            C[(size_t)(row0 + tm + i) * 1024 + col0 + tn + j] = acc[i][j] + bias[col0 + tn + j];
}

// ---------------- Recurrent scan (R6: best measured, 3.77 us/step) ----------
// 32 persistent WGs, 2-hop owner-reduce exchange through agent-scope LLC.
// Per step:
//   p1: r_j partial dots (weights w1_* in VGPRs) | B1
//   p2: rank-32 partials (w2a_*/w2b_* in VGPRs) -> tagged agent stores
//   RT1: owner polls 32 partials (1 poller/slot), butterfly-reduce, tanh
//        -> tagged h broadcast (lane0) + out store (lane1)
//   RT2: all poll tagged h, refill LDS | B2
// Measured floor: 2 LLC hops x ~1.65us + ~0.45us compute = 3.7-3.8 us/step;
// all 1-hop variants (atomic RMW or redundant gather) measured slower.
__global__ __launch_bounds__(RT, 1) void gru_rec(
    const float* __restrict__ xT, const float* __restrict__ xR,
    const float* __restrict__ hRW, const float* __restrict__ hW,
    const float* __restrict__ hRB, const float* __restrict__ hB,
    const float* __restrict__ h0, float* __restrict__ out,
    unsigned long long* __restrict__ P,     // [2][KWG][NN]
    unsigned long long* __restrict__ hbc)   // [2][NN]
{
    const int g = blockIdx.x;
    const int tid = threadIdx.x;
    const int lane = tid & 63;
    const int wave = tid >> 6;

    __shared__ __align__(16) float hsh[1088];  // chunk c at c*68 (2-way max)
    __shared__ __align__(16) float rh[32];

    // phase 1 mapping: column j (0..31), 16 lanes (c) split i into 64-chunks
    const int j = (wave << 2) | (lane >> 4);
    const int c = lane & 15;
    const bool leader1 = (c == 0);
    const int colj = g * 32 + j;

    // ---- weights: named vectors, register-pinned ----
#define LD_W1(q) f32x4 w1_##q = { \
        hRW[(size_t)(c * 64 + 4 * q + 0) * NN + colj], \
        hRW[(size_t)(c * 64 + 4 * q + 1) * NN + colj], \
        hRW[(size_t)(c * 64 + 4 * q + 2) * NN + colj], \
        hRW[(size_t)(c * 64 + 4 * q + 3) * NN + colj] };
    REP16(LD_W1)

    const int n0 = tid, n1 = tid + RT;
    const int pi0 = n0 + (n0 >> 6) * 4, pi1 = n1 + (n1 >> 6) * 4;
#define LD_W2A(q) f32x4 w2a_##q = { \
        hW[(size_t)(g * 32 + 4 * q + 0) * NN + n0], \
        hW[(size_t)(g * 32 + 4 * q + 1) * NN + n0], \
        hW[(size_t)(g * 32 + 4 * q + 2) * NN + n0], \
        hW[(size_t)(g * 32 + 4 * q + 3) * NN + n0] };
    REP8(LD_W2A)
#define LD_W2B(q) f32x4 w2b_##q = { \
        hW[(size_t)(g * 32 + 4 * q + 0) * NN + n1], \
        hW[(size_t)(g * 32 + 4 * q + 1) * NN + n1], \
        hW[(size_t)(g * 32 + 4 * q + 2) * NN + n1], \
        hW[(size_t)(g * 32 + 4 * q + 3) * NN + n1] };
    REP8(LD_W2B)

#define PIN_W1(q)  asm volatile("" : "+v"(w1_##q));
#define PIN_W2A(q) asm volatile("" : "+v"(w2a_##q));
#define PIN_W2B(q) asm volatile("" : "+v"(w2b_##q));
    REP16(PIN_W1)
    REP8(PIN_W2A)
    REP8(PIN_W2B)

    // owner-reduce mapping: column jj (0..31) x 16 reducer lanes (cc)
    const int jj = tid >> 4, cc = tid & 15;
    const int mjj = g * 32 + jj;
    const float hBo = hB[mjj];

    const int mj = colj;
    const int pij = mj + (mj >> 6) * 4;
    const float hRBj = hRB[mj];

    hsh[pi0] = h0[n0];
    hsh[pi1] = h0[n1];
    __syncthreads();

    // 1-step-ahead input prefetch (hides HBM latency of the xT/xR stream)
    float xr_n  = leader1   ? xR[mj]  : 0.f;
    float xto_n = (cc == 0) ? xT[mjj] : 0.f;

    for (int t = 0; t < T_STEPS; ++t) {
        const unsigned tag = (unsigned)(t + 1);
        unsigned long long* __restrict__ Pb = P   + (size_t)(t & 1) * KWG * NN;
        unsigned long long* __restrict__ Hb = hbc + (size_t)(t & 1) * NN;

        const float xr = xr_n, xto = xto_n;
        if (t + 1 < T_STEPS) {
            if (leader1) xr_n  = xR[(size_t)(t + 1) * NN + mj];
            if (cc == 0) xto_n = xT[(size_t)(t + 1) * NN + mjj];
        }

        // ---- phase 1: r-gemv partials over own 64-chunk (weights in VGPRs)
        f32x4 acc = {0.f, 0.f, 0.f, 0.f};
#define FMA_W1(q) { \
        const f32x4 hv = *reinterpret_cast<const f32x4*>(&hsh[c * 68 + 4 * q]); \
        acc += hv * w1_##q; }
        REP16(FMA_W1)
        float s = (acc.x + acc.y) + (acc.z + acc.w);
        s += __shfl_xor(s, 1); s += __shfl_xor(s, 2);
        s += __shfl_xor(s, 4); s += __shfl_xor(s, 8);
        if (leader1) rh[j] = fast_sigmoid(xr + hRBj + s) * hsh[pij];
        __syncthreads();

        // ---- phase 2: rank-32 partials for n0, n1 (weights in VGPRs)
        f32x4 aa = {0.f, 0.f, 0.f, 0.f}, bb = {0.f, 0.f, 0.f, 0.f};
#define FMA_W2(q) { \
        const f32x4 rv = *reinterpret_cast<const f32x4*>(&rh[4 * q]); \
        aa += rv * w2a_##q; bb += rv * w2b_##q; }
        REP8(FMA_W2)
        const float p0 = (aa.x + aa.y) + (aa.z + aa.w);
        const float p1 = (bb.x + bb.y) + (bb.z + bb.w);
        __hip_atomic_store(&Pb[(size_t)g * NN + n0],
            ((unsigned long long)tag << 32) | (unsigned)__float_as_uint(p0),
            __ATOMIC_RELAXED, __HIP_MEMORY_SCOPE_AGENT);
        __hip_atomic_store(&Pb[(size_t)g * NN + n1],
            ((unsigned long long)tag << 32) | (unsigned)__float_as_uint(p1),
            __ATOMIC_RELAXED, __HIP_MEMORY_SCOPE_AGENT);

        // ---- RT1: owner-reduce — poll partials from regions cc and cc+16
        float hn;
        {
            unsigned long long va = 0, vb = 0;
            bool fa = false, fb = false;
            do {
                if (!fa) { va = __hip_atomic_load(&Pb[(size_t)cc * NN + mjj],
                             __ATOMIC_RELAXED, __HIP_MEMORY_SCOPE_AGENT);
                           fa = ((unsigned)(va >> 32) == tag); }
                if (!fb) { vb = __hip_atomic_load(&Pb[(size_t)(cc + 16) * NN + mjj],
                             __ATOMIC_RELAXED, __HIP_MEMORY_SCOPE_AGENT);
                           fb = ((unsigned)(vb >> 32) == tag); }
            } while (!(fa && fb));
            float s2 = __uint_as_float((unsigned)va) + __uint_as_float((unsigned)vb);
            s2 += __shfl_xor(s2, 1); s2 += __shfl_xor(s2, 2);
            s2 += __shfl_xor(s2, 4); s2 += __shfl_xor(s2, 8);
            hn = fast_tanh(xto ? xto + s2 + hBo : s2 + hBo);
            // all 16 lanes hold s2; recompute hn uniformly to split stores
            hn = fast_tanh(__shfl(xto, (tid & ~15) & 63, 64) + s2 + hBo);
            if (cc == 0) {
                __hip_atomic_store(&Hb[mjj],
                    ((unsigned long long)tag << 32) | (unsigned)__float_as_uint(hn),
                    __ATOMIC_RELAXED, __HIP_MEMORY_SCOPE_AGENT);
            }
            if (cc == 1) out[(size_t)t * NN + mjj] = hn;
        }

        // ---- RT2: poll h broadcast, refill LDS h
        {
            unsigned long long ua = 0, ub = 0;
            bool fa = false, fb = false;
            do {
                if (!fa) { ua = __hip_atomic_load(&Hb[n0], __ATOMIC_RELAXED,
                             __HIP_MEMORY_SCOPE_AGENT);
                           fa = ((unsigned)(ua >> 32) == tag); }
                if (!fb) { ub = __hip_atomic_load(&Hb[n1], __ATOMIC_RELAXED,
                             __HIP_MEMORY_SCOPE_AGENT);
                           fb = ((unsigned)(ub >> 32) == tag); }
            } while (!(fa && fb));
            hsh[pi0] = __uint_as_float((unsigned)ua);
            hsh[pi1] = __uint_as_float((unsigned)ub);
        }
        __syncthreads();
    }
}

extern "C" void kernel_launch(void* const* d_in, const int* in_sizes, int n_in,
                              void* d_out, int out_size, void* d_ws, size_t ws_size,
                              hipStream_t stream) {
    const float* x   = (const float*)d_in[0];
    const float* Wx  = (const float*)d_in[1];
    const float* bx  = (const float*)d_in[2];
    // d_in[3]=Wu, d_in[4]=bu unused: update gate cancels in the reference
    const float* Wr  = (const float*)d_in[5];
    const float* br  = (const float*)d_in[6];
    const float* hW  = (const float*)d_in[7];
    // d_in[8]=hUW unused
    const float* hRW = (const float*)d_in[9];
    const float* hB  = (const float*)d_in[10];
    // d_in[11]=hUB unused
    const float* hRB = (const float*)d_in[12];
    const float* h0  = (const float*)d_in[13];
    float* out = (float*)d_out;

    char* ws = (char*)d_ws;
    float* xT = (float*)(ws);                               // 32 MB
    float* xR = (float*)(ws + 33554432);                    // 32 MB
    unsigned long long* P   = (unsigned long long*)(ws + 67108864);          // 512 KB
    unsigned long long* hbc = (unsigned long long*)(ws + 67108864 + 524288); // 16 KB

    // clear tags once per launch (covers harness 0xAA poison; replay-to-replay
    // tag collisions are benign by determinism, but zeroing removes all doubt)
    hipMemsetAsync(P, 0, (2 * KWG * NN + 2 * NN) * sizeof(unsigned long long), stream);

    gemm_bias<<<dim3(16, 128), 256, 0, stream>>>(x, Wx, bx, xT);
    gemm_bias<<<dim3(16, 128), 256, 0, stream>>>(x, Wr, br, xR);

    gru_rec<<<dim3(KWG), RT, 0, stream>>>(xT, xR, hRW, hW, hRB, hB, h0,
                                          out, P, hbc);
}